// Round 6
// baseline (128.445 us; speedup 1.0000x reference)
//
#include <hip/hip_runtime.h>
#include <hip/hip_bf16.h>
#include <math.h>
#include <stdint.h>

// Problem: B=64, SQ=64, SD=512, H=128
#define BB 64
#define SQN 64
#define SDN 512
#define HH 128

typedef __attribute__((ext_vector_type(8))) short bf16x8;     // 8 bf16 = 4 VGPRs
typedef __attribute__((ext_vector_type(16))) float f32x16;    // 16 acc regs

__device__ __forceinline__ short f2bf(float f) {
  union { float f; unsigned u; } x; x.f = f;
  unsigned r = x.u + 0x7fffu + ((x.u >> 16) & 1u);   // RNE
  return (short)(r >> 16);
}

__device__ __forceinline__ void gl_lds16(const short* g, short* l) {
  __builtin_amdgcn_global_load_lds(
      (const __attribute__((address_space(1))) unsigned int*)g,
      (__attribute__((address_space(3))) unsigned int*)l, 16, 0, 0);
}

// ---- fused compact + fp32->bf16 convert (unchanged) -------------------------
__global__ __launch_bounds__(256)
void convert_all(const float* __restrict__ q, const float* __restrict__ dp,
                 const float* __restrict__ dn,
                 const int* __restrict__ mp, const int* __restrict__ mn,
                 short* __restrict__ oq, short* __restrict__ od,
                 int* __restrict__ nchunks, int* __restrict__ nvalid,
                 int* __restrict__ counter) {
  const int D_BLOCKS = (2 * BB * SDN) / 8;   // 8192 (8 rows/block, 32 thr/row)
  if (blockIdx.x < D_BLOCKS) {
    const int bs = blockIdx.x >> 6;          // 64 blocks per (side*64+b)
    const int j0 = (blockIdx.x & 63) * 8;    // first compacted row of block
    const int side = bs >> 6, b = bs & 63;
    const int* mask = (side ? mn : mp) + b * SDN;

    __shared__ int s_perm[8];
    __shared__ int s_pad32;

    if (threadIdx.x < 64) {                  // wave 0: exclusive scan of mask
      const int ln = threadIdx.x;
      int mreg[8];
      #pragma unroll
      for (int it = 0; it < 8; ++it) mreg[it] = mask[it * 64 + ln];
      int run = 0;
      #pragma unroll
      for (int it = 0; it < 8; ++it) {
        unsigned long long bal = __ballot(mreg[it] != 0);
        int pos = run + __popcll(bal & ((1ull << ln) - 1ull));
        if (mreg[it]) {
          unsigned rel = (unsigned)(pos - j0);
          if (rel < 8u) s_perm[rel] = it * 64 + ln;
        }
        run += (int)__popcll(bal);
      }
      if (ln < 8 && j0 + ln >= run) s_perm[ln] = -1;   // zero-fill slots
      if (ln == 0) {
        s_pad32 = (run + 31) & ~31;
        if (j0 == 0) {                       // one writer per bs
          nchunks[bs] = ((run + 127) & ~127) >> 7;
          nvalid[bs]  = run;
        }
      }
    }
    __syncthreads();

    const int j = j0 + (threadIdx.x >> 5);
    if (j >= s_pad32) return;                // never computed by maxsim
    const int l32 = threadIdx.x & 31;
    const int src_t = s_perm[threadIdx.x >> 5];
    const float* srcmat = side ? dn : dp;
    float4 v = make_float4(0.f, 0.f, 0.f, 0.f);
    if (src_t >= 0)
      v = ((const float4*)(srcmat + ((size_t)b * SDN + src_t) * HH))[l32];
    short4 o; o.x = f2bf(v.x); o.y = f2bf(v.y); o.z = f2bf(v.z); o.w = f2bf(v.w);
    *(short4*)&od[((size_t)bs * SDN + j) * HH + l32 * 4] = o;
  } else {
    if (blockIdx.x == D_BLOCKS && threadIdx.x == 0) *counter = 0;  // maxsim ticket
    int i = (blockIdx.x - D_BLOCKS) * 256 + threadIdx.x;  // float4 index, exact
    float4 v = ((const float4*)q)[i];
    short4 o; o.x = f2bf(v.x); o.y = f2bf(v.y); o.z = f2bf(v.z); o.w = f2bf(v.w);
    *(short4*)&oq[i * 4] = o;
  }
}

// Persistent maxsim — ROUND 6: counted-vmcnt ring pipeline (T3+T4).
//
// ROUND-5 POST-MORTEM: maxsim invariant at 44-48us across wave-count x2,
// LDS-traffic x4, chain-count x2. MfmaUtil pinned ~30% = the known 2-phase
// barrier-drain ceiling (m233): per-chunk wall ~9.5k cyc vs ~4.1k max-pipe
// work; __syncthreads' vmcnt(0)+lgkmcnt(0) drain serializes the phases.
//
// NEW STRUCTURE: ring of 4 x 64-row (16KB) LDS buffers, prefetch depth 2.
// Per iteration: [issue P(k+2): exactly 2 gl_lds16/wave, UNTRIMMED so the
// count is uniform] [s_waitcnt vmcnt(4): own P(k) loads done, P(k+1)/P(k+2)
// stay IN FLIGHT across the barrier] [raw s_barrier] [compute chunk k].
// No vmcnt(0) in the steady loop. Race audit:
//  - ring[(k+2)&3] overwritten by P(k+2) (issued after this wave passed
//    barrier(k-1)) was last read in compute(k-2), finished by ALL waves
//    before barrier(k-1). One-barrier separation -> safe.
//  - compute(k) reads data staged by ALL waves' P(k): each wave waited
//    vmcnt(4) (its own P(k) retired, incl. LDS write) before barrier(k).
//  - gl_lds are the ONLY VMEM in the loop (score stores deferred to LDS
//    s_out, flushed once at kernel end) -> vmcnt counting exact; any
//    compiler spills only make vmcnt(4) MORE conservative (oldest-first).
//  - finalize (4x/block) keeps __syncthreads (full drain = early wait only).
// Compute trim unchanged: last chunk computes ceil((valid-64*tc)/32) of 2
// 32-row tiles; staged-but-untouched rows carry garbage that is never read
// into MFMA. fmax re-partition across waves is exact (assoc/comm); v0+v1
// pairing + xor tree verbatim -> bitwise-identical scores and loss.
//
// XCD swizzle: lid%8 picks the XCD; each XCD owns 4 whole bgroups x 16
// a-slices. Wave = (query aw, t-half th): one dfrag feeds acc0/acc1.
// d_lds: [4][64][128] bf16, 16B chunks XOR-swizzled (c^(row&15)), staging +
// ds_read_b128 conflict-free. Handoff: sc1 relaxed agent atomics +
// vmcnt(0) release; NO __threadfence (round-2: wbl2+inv cache nuke).
__global__ __launch_bounds__(512, 4)
void maxsim_kernel(const short* __restrict__ qb,
                   const short* __restrict__ dc,
                   const int* __restrict__ nchunks,   // unused (kept for ABI)
                   const int* __restrict__ nvalid,
                   float* __restrict__ scores,
                   int* __restrict__ counter,
                   float* __restrict__ out) {
  const int lid  = blockIdx.x + 16 * blockIdx.y;   // 0..511
  const int xcd  = lid & 7;
  const int slot0= lid >> 3;                        // 0..63 within XCD
  const int aslc = slot0 & 15;
  const int bs0  = (xcd + 8 * (slot0 >> 4)) * 4;    // bgroup*4

  __shared__ __align__(16) short d_lds[4][64 * 128];  // 4 x 16 KB ring
  __shared__ float s_fin[4 * 64];                     // th1 -> th0 exchange
  __shared__ float s_out[16];                         // deferred scores
  __shared__ int s_ticket;
  __shared__ float part[16];

  const int tid = threadIdx.x;       // 0..511
  const int ln  = tid & 63;
  const int w   = tid >> 6;          // 0..7
  const int l31 = ln & 31;
  const int kh  = ln >> 5;
  const int aw  = w >> 1;            // 0..3: which query of this slice
  const int th  = w & 1;             // 32-row t-tile owned by this wave
  const int a   = aslc * 4 + aw;

  int nch[4], nvv[4];                // 64-row chunks per bs (block-uniform)
  #pragma unroll
  for (int i = 0; i < 4; ++i) {
    nvv[i] = nvalid[bs0 + i];
    nch[i] = (nvv[i] + 63) >> 6;
  }

  // ---- q as B-operand, BOTH s-halves: n = half*32+l31, k = kc*16+kh*8 ----
  bf16x8 qfrag[2][8];
  #pragma unroll
  for (int half = 0; half < 2; ++half) {
    const short* qrow = qb + ((size_t)a * SQN + half * 32 + l31) * HH + kh * 8;
    #pragma unroll
    for (int kc = 0; kc < 8; ++kc)
      qfrag[half][kc] = *(const bf16x8*)(qrow + kc * 16);
  }

  float rmaxh[2] = {0.f, 0.f};   // masked-zero trick: true max >= 0

  // stage one full 64-row chunk (untrimmed; 2 gl_lds16 per wave, constant)
  auto STAGE = [&](int pbi, int ptc, int sl) {
    const short* dsrc = dc + ((size_t)(bs0 + pbi) * SDN + ptc * 64) * HH;
    short* dst = &d_lds[sl][0];
    #pragma unroll
    for (int it = 0; it < 2; ++it) {
      int f = it * 512 + tid;
      int row = f >> 4;                       // 0..63 within chunk
      int c = (f & 15) ^ (row & 15);
      gl_lds16(&dsrc[row * HH + c * 8], &dst[(it * 512 + w * 64) * 8]);
    }
  };

  // ---- prologue: P(0) -> slot0, P(1) -> slot1 (NT = sum nch >= 4) ----
  int pbi = 0, ptc = 0;
  STAGE(pbi, ptc, 0);
  if (++ptc == nch[pbi]) { ptc = 0; ++pbi; }
  STAGE(pbi, ptc, 1);
  if (++ptc == nch[pbi]) { ptc = 0; ++pbi; }

  int cbi = 0, ctc = 0, sl = 0;
  for (;;) {
    // ---- issue P(k+2) into ring[(sl+2)&3]; dummy re-stage of (0,0) at tail ----
    {
      int qbi2 = (pbi < 4) ? pbi : 0;
      int qtc2 = (pbi < 4) ? ptc : 0;
      STAGE(qbi2, qtc2, (sl + 2) & 3);
      if (pbi < 4) { if (++ptc == nch[pbi]) { ptc = 0; ++pbi; } }
    }

    // ---- counted wait: own P(k) retired; P(k+1),P(k+2) stay in flight ----
    asm volatile("s_waitcnt vmcnt(4)" ::: "memory");
    __builtin_amdgcn_s_barrier();

    // ---- compute chunk (cbi,ctc): this wave's 32-row tile, both s-halves ----
    const int ntt = (ctc == nch[cbi] - 1)
                        ? ((nvv[cbi] - (ctc << 6) + 31) >> 5)   // 1..2, uniform
                        : 2;
    if (th < ntt) {
      const short* bufp = &d_lds[sl][0];
      int trow = th * 32 + l31;
      int tm = trow & 15;
      const short* bbase = &bufp[trow * HH];
      f32x16 acc0 = {0,0,0,0,0,0,0,0,0,0,0,0,0,0,0,0};
      f32x16 acc1 = {0,0,0,0,0,0,0,0,0,0,0,0,0,0,0,0};
      #pragma unroll
      for (int kc = 0; kc < 8; ++kc) {
        int c = (kc * 2 + kh) ^ tm;
        bf16x8 dfrag = *(const bf16x8*)&bbase[c * 8];  // A: m = t = trow
        acc0 = __builtin_amdgcn_mfma_f32_32x32x16_bf16(dfrag, qfrag[0][kc], acc0, 0, 0, 0);
        acc1 = __builtin_amdgcn_mfma_f32_32x32x16_bf16(dfrag, qfrag[1][kc], acc1, 0, 0, 0);
      }
      // C: col = l31 = s (within half), rows = 16 t's of this lane's kh group
      float m0 = acc0[0], m1 = acc1[0];
      #pragma unroll
      for (int r = 1; r < 16; ++r) {
        m0 = fmaxf(m0, acc0[r]);
        m1 = fmaxf(m1, acc1[r]);
      }
      rmaxh[0] = fmaxf(rmaxh[0], m0);
      rmaxh[1] = fmaxf(rmaxh[1], m1);
    }

    // ---- advance compute; finalize bs when it wraps (block-uniform) ----
    const int obi = cbi;
    const bool fin = (++ctc == nch[cbi]);
    if (fin) {
      ctc = 0; ++cbi;
      float v0 = fmaxf(rmaxh[0], __shfl_xor(rmaxh[0], 32));  // merge kh halves
      float v1 = fmaxf(rmaxh[1], __shfl_xor(rmaxh[1], 32));
      if (th && kh == 0) {                 // publish t-half-1 maxes
        s_fin[aw * 64 + l31]      = v0;
        s_fin[aw * 64 + 32 + l31] = v1;
      }
      __syncthreads();                     // full drain: early-wait only, 4x/block
      if (!th) {
        v0 = fmaxf(v0, s_fin[aw * 64 + l31]);        // exact max merge
        v1 = fmaxf(v1, s_fin[aw * 64 + 32 + l31]);
        float s = v0 + v1;                 // original operand order
        s += __shfl_xor(s, 1);  s += __shfl_xor(s, 2);  s += __shfl_xor(s, 4);
        s += __shfl_xor(s, 8);  s += __shfl_xor(s, 16);
        if (ln == 0) s_out[aw * 4 + obi] = s;   // defer global store (LDS only)
      }
      rmaxh[0] = 0.f; rmaxh[1] = 0.f;
    }

    if (cbi == 4) break;
    sl = (sl + 1) & 3;
  }

  // ---- flush deferred scores, then fused loss via last-block ticket ----
  __syncthreads();                          // s_out visible; drains all VMEM
  if (w == 0 && ln < 16) {
    int ai = ln >> 2, bi = ln & 3;
    __hip_atomic_store(&scores[(size_t)(aslc * 4 + ai) * (2 * BB) + bs0 + bi],
                       s_out[ln], __ATOMIC_RELAXED, __HIP_MEMORY_SCOPE_AGENT);
  }
  asm volatile("s_waitcnt vmcnt(0)" ::: "memory");  // sc1 stores at LLC
  if (tid == 0)
    s_ticket = __hip_atomic_fetch_add(counter, 1,
                                      __ATOMIC_RELAXED, __HIP_MEMORY_SCOPE_AGENT);
  __syncthreads();
  if (s_ticket != 511) return;

  // Bitwise-identical replica of the original 16-partial loss reduction:
  // part[vp] (vp=0..15) covers rows 4vp..4vp+3; waves 0..3 compute vp=4w..4w+3;
  // wave 0 then runs the exact 16-lane xor tree. sc1 loads read the LLC.
  if (w < 4) {
    #pragma unroll
    for (int q8 = 0; q8 < 4; ++q8) {
      int vp = w * 4 + q8;
      float acc = 0.f;
      #pragma unroll
      for (int i = 0; i < 4; ++i) {
        int r = vp * 4 + i;
        float v0 = __hip_atomic_load(&scores[r * 128 + ln],
                                     __ATOMIC_RELAXED, __HIP_MEMORY_SCOPE_AGENT);
        float v1 = __hip_atomic_load(&scores[r * 128 + 64 + ln],
                                     __ATOMIC_RELAXED, __HIP_MEMORY_SCOPE_AGENT);
        float mx = fmaxf(v0, v1);
        #pragma unroll
        for (int off = 32; off >= 1; off >>= 1) mx = fmaxf(mx, __shfl_xor(mx, off));
        float e = __expf(v0 - mx) + __expf(v1 - mx);
        #pragma unroll
        for (int off = 32; off >= 1; off >>= 1) e += __shfl_xor(e, off);
        float lse = mx + __logf(e);
        float diag = __shfl(v0, r);   // r < 64, diagonal lives in v0 at lane r
        acc += lse - diag;
      }
      if (ln == 0) part[vp] = acc;
    }
  }
  __syncthreads();
  if (w == 0) {
    float v = (ln < 16) ? part[ln] : 0.f;
    #pragma unroll
    for (int off = 8; off >= 1; off >>= 1) v += __shfl_xor(v, off);
    if (ln == 0) out[0] = v * (1.0f / 64.0f);
  }
}

extern "C" void kernel_launch(void* const* d_in, const int* in_sizes, int n_in,
                              void* d_out, int out_size, void* d_ws, size_t ws_size,
                              hipStream_t stream) {
  const float* q        = (const float*)d_in[0];
  const float* d_pos    = (const float*)d_in[1];
  const float* d_neg    = (const float*)d_in[2];
  const int*   mask_pos = (const int*)d_in[3];
  const int*   mask_neg = (const int*)d_in[4];

  // ws layout: q_bf 1 MB | d_c 16 MB | nchunks | nvalid | scores | counter
  short* q_bf = (short*)d_ws;                                  // 524288 shorts
  short* d_c  = q_bf + (size_t)BB * SQN * HH;                  // 8388608 shorts
  int*   nchunks = (int*)(d_c + (size_t)2 * BB * SDN * HH);    // 128 ints
  int*   nvalid  = nchunks + 128;                              // 128 ints
  float* scores  = (float*)(nvalid + 128);                     // 8192 floats
  int*   counter = (int*)(scores + 64 * 128);                  // 1 int

  const int D_BLOCKS = (2 * BB * SDN) / 8;          // 8192
  const int Q_BLOCKS = (BB * SQN * HH / 4) / 256;   // 512
  convert_all<<<D_BLOCKS + Q_BLOCKS, 256, 0, stream>>>(
      q, d_pos, d_neg, mask_pos, mask_neg, q_bf, d_c, nchunks, nvalid, counter);

  dim3 grid(16 /*a-slices*/, 32 /*b-groups*/);
  maxsim_kernel<<<grid, 512, 0, stream>>>(q_bf, d_c, nchunks, nvalid, scores,
                                          counter, (float*)d_out);
}